// Round 1
// baseline (151.955 us; speedup 1.0000x reference)
//
#include <hip/hip_runtime.h>
#include <math.h>

#define Bn 256
#define Nn 1024
#define Dn 128
#define Hn 8
#define HDn 16
#define NEG_INF -1.0e15f

// ---------------- K0: Q = h_c @ Wq.T + bq ----------------
__global__ __launch_bounds__(128) void k_q(
    const float* __restrict__ h_g, const float* __restrict__ first,
    const float* __restrict__ last, const float* __restrict__ context,
    const float* __restrict__ Wq, const float* __restrict__ bq,
    float* __restrict__ Qout)
{
    __shared__ __align__(16) float hc[3 * Dn + 2];
    const int b = blockIdx.x;
    const int t = threadIdx.x;
    hc[t]          = h_g[b * Dn + t];
    hc[Dn + t]     = first[b * Dn + t];
    hc[2 * Dn + t] = last[b * Dn + t];
    if (t < 2) hc[3 * Dn + t] = context[b * 2 + t];
    __syncthreads();

    const float2* w2 = (const float2*)(Wq + (size_t)t * (3 * Dn + 2));
    const float2* h2 = (const float2*)hc;
    float acc = bq[t];
    for (int k = 0; k < (3 * Dn + 2) / 2; ++k) {
        float2 w = w2[k], h = h2[k];
        acc += w.x * h.x + w.y * h.y;
    }
    Qout[b * Dn + t] = acc;
}

// ---------------- K1: per-(b,h) attention: scores -> softmax -> u ----------------
__global__ __launch_bounds__(256) void k_attn(
    const float* __restrict__ Q, const float* __restrict__ K,
    const float* __restrict__ V, const int* __restrict__ mask,
    float* __restrict__ Uout)
{
    __shared__ __align__(16) float sE[Nn];   // scores, then exp weights
    __shared__ float sQ[HDn];
    __shared__ float sRed[8];                // [0..3] wave max, [4..7] wave sum
    __shared__ float sUp[4][HDn];            // per-wave u partials

    const int bh = blockIdx.x;
    const int b = bh >> 3;
    const int tid = threadIdx.x;
    const int lane = tid & 63, wave = tid >> 6;

    if (tid < HDn) sQ[tid] = Q[b * Dn + (bh & 7) * HDn + tid];
    __syncthreads();
    float q[HDn];
#pragma unroll
    for (int j = 0; j < HDn; ++j) q[j] = sQ[j];

    const float4* Kp = (const float4*)(K + (size_t)bh * Nn * HDn);
    const int* mrow = mask + b * Nn;

    // scores
    float lmax = NEG_INF;
#pragma unroll
    for (int i = 0; i < 4; ++i) {
        const int n = tid + i * 256;
        float4 k0 = Kp[n * 4 + 0], k1 = Kp[n * 4 + 1];
        float4 k2 = Kp[n * 4 + 2], k3 = Kp[n * 4 + 3];
        float s = q[0] * k0.x + q[1] * k0.y + q[2] * k0.z + q[3] * k0.w
                + q[4] * k1.x + q[5] * k1.y + q[6] * k1.z + q[7] * k1.w
                + q[8] * k2.x + q[9] * k2.y + q[10] * k2.z + q[11] * k2.w
                + q[12] * k3.x + q[13] * k3.y + q[14] * k3.z + q[15] * k3.w;
        s *= 0.25f;                              // / sqrt(HD)=4
        s = (mrow[n] == 0) ? NEG_INF : s;
        sE[n] = s;
        lmax = fmaxf(lmax, s);
    }
    // block max
#pragma unroll
    for (int o = 32; o >= 1; o >>= 1) lmax = fmaxf(lmax, __shfl_xor(lmax, o, 64));
    if (lane == 0) sRed[wave] = lmax;
    __syncthreads();
    const float m = fmaxf(fmaxf(sRed[0], sRed[1]), fmaxf(sRed[2], sRed[3]));

    // exp + sum
    float lsum = 0.f;
#pragma unroll
    for (int i = 0; i < 4; ++i) {
        const int n = tid + i * 256;
        const float e = __expf(sE[n] - m);
        sE[n] = e;
        lsum += e;
    }
#pragma unroll
    for (int o = 32; o >= 1; o >>= 1) lsum += __shfl_xor(lsum, o, 64);
    if (lane == 0) sRed[4 + wave] = lsum;
    __syncthreads();
    const float invsum = 1.0f / (sRed[4] + sRed[5] + sRed[6] + sRed[7]);

    // u = sum_n e[n] * V[n,:]   (d4 = float4 column, g = n-group)
    const float4* Vp = (const float4*)(V + (size_t)bh * Nn * HDn);
    const int d4 = tid & 3, g = tid >> 2;
    float4 acc = {0.f, 0.f, 0.f, 0.f};
#pragma unroll
    for (int i = 0; i < 16; ++i) {
        const int n = g + 64 * i;
        const float e = sE[n];
        const float4 v = Vp[n * 4 + d4];
        acc.x += e * v.x; acc.y += e * v.y; acc.z += e * v.z; acc.w += e * v.w;
    }
#pragma unroll
    for (int o = 4; o <= 32; o <<= 1) {
        acc.x += __shfl_xor(acc.x, o, 64);
        acc.y += __shfl_xor(acc.y, o, 64);
        acc.z += __shfl_xor(acc.z, o, 64);
        acc.w += __shfl_xor(acc.w, o, 64);
    }
    if (lane < 4) {
        sUp[wave][lane * 4 + 0] = acc.x;
        sUp[wave][lane * 4 + 1] = acc.y;
        sUp[wave][lane * 4 + 2] = acc.z;
        sUp[wave][lane * 4 + 3] = acc.w;
    }
    __syncthreads();
    if (tid < HDn) {
        const float u = (sUp[0][tid] + sUp[1][tid] + sUp[2][tid] + sUp[3][tid]) * invsum;
        Uout[b * Dn + (bh & 7) * HDn + tid] = u;
    }
}

// ---------------- K2: u2 = u@Wo.T + bo; pointer logits; softmax; argmax ----------------
__global__ __launch_bounds__(512) void k_ptr(
    const float* __restrict__ U, const float* __restrict__ Wo,
    const float* __restrict__ bo, const float* __restrict__ K_lg,
    const int* __restrict__ mask, float* __restrict__ out)
{
    __shared__ __align__(16) float sU[Dn];
    __shared__ __align__(16) float sU2[Dn];
    __shared__ __align__(16) float sL[Nn];
    __shared__ float sRv[8];
    __shared__ int   sRi[8];
    __shared__ float sRs[8];

    const int b = blockIdx.x;
    const int tid = threadIdx.x;
    const int lane = tid & 63, wave = tid >> 6;

    if (tid < Dn) sU[tid] = U[b * Dn + tid];
    __syncthreads();
    if (tid < Dn) {
        const float4* wrow = (const float4*)(Wo + (size_t)tid * Dn);
        const float4* su4 = (const float4*)sU;
        float acc = bo[tid];
#pragma unroll
        for (int k = 0; k < Dn / 4; ++k) {
            const float4 w = wrow[k], u = su4[k];
            acc += w.x * u.x + w.y * u.y + w.z * u.z + w.w * u.w;
        }
        sU2[tid] = acc;
    }
    __syncthreads();

    // logits: 16 groups of 32 lanes, group computes one n per iteration
    const float4* Kl = (const float4*)(K_lg + (size_t)b * Nn * Dn);
    const int* mrow = mask + b * Nn;
    const float4* su2 = (const float4*)sU2;
    const int grp = tid >> 5, l32 = tid & 31;
    const float sc = 1.0f / sqrtf(128.0f);
#pragma unroll 8
    for (int it = 0; it < Nn / 16; ++it) {
        const int n = it * 16 + grp;
        const float4 kl = Kl[(size_t)n * 32 + l32];
        const float4 u2 = su2[l32];
        float p = kl.x * u2.x + kl.y * u2.y + kl.z * u2.z + kl.w * u2.w;
#pragma unroll
        for (int o = 16; o >= 1; o >>= 1) p += __shfl_xor(p, o, 64);
        if (l32 == 0) {
            const float lg = 10.0f * tanhf(p * sc);
            sL[n] = (mrow[n] == 0) ? NEG_INF : lg;
        }
    }
    __syncthreads();

    // block argmax (first-occurrence tie-break, matching jnp.argmax)
    float bv = NEG_INF; int bi = 0;
#pragma unroll
    for (int i = 0; i < 2; ++i) {
        const int n = tid + i * 512;
        const float v = sL[n];
        if (v > bv || (v == bv && n < bi)) { bv = v; bi = n; }
    }
#pragma unroll
    for (int o = 32; o >= 1; o >>= 1) {
        const float ov = __shfl_xor(bv, o, 64);
        const int oi = __shfl_xor(bi, o, 64);
        if (ov > bv || (ov == bv && oi < bi)) { bv = ov; bi = oi; }
    }
    if (lane == 0) { sRv[wave] = bv; sRi[wave] = bi; }
    __syncthreads();
    bv = sRv[0]; bi = sRi[0];
#pragma unroll
    for (int w = 1; w < 8; ++w) {
        const float ov = sRv[w]; const int oi = sRi[w];
        if (ov > bv || (ov == bv && oi < bi)) { bv = ov; bi = oi; }
    }

    // sum of exp(l - max); prob at argmax = 1/sum
    float lsum = 0.f;
#pragma unroll
    for (int i = 0; i < 2; ++i) lsum += __expf(sL[tid + i * 512] - bv);
#pragma unroll
    for (int o = 32; o >= 1; o >>= 1) lsum += __shfl_xor(lsum, o, 64);
    if (lane == 0) sRs[wave] = lsum;
    __syncthreads();
    if (tid == 0) {
        float tot = 0.f;
#pragma unroll
        for (int w = 0; w < 8; ++w) tot += sRs[w];
        out[b] = (float)bi;            // vertexes (as float32 values)
        out[Bn + b] = 1.0f / tot;      // probs
    }
}

extern "C" void kernel_launch(void* const* d_in, const int* in_sizes, int n_in,
                              void* d_out, int out_size, void* d_ws, size_t ws_size,
                              hipStream_t stream) {
    // inputs (setup_inputs order): x, h_g, first, last, context, K, V, K_lg,
    //                              Wq, bq, Wo, bo, mask, t
    const float* h_g     = (const float*)d_in[1];
    const float* first   = (const float*)d_in[2];
    const float* last    = (const float*)d_in[3];
    const float* context = (const float*)d_in[4];
    const float* K       = (const float*)d_in[5];
    const float* V       = (const float*)d_in[6];
    const float* K_lg    = (const float*)d_in[7];
    const float* Wq      = (const float*)d_in[8];
    const float* bq      = (const float*)d_in[9];
    const float* Wo      = (const float*)d_in[10];
    const float* bo      = (const float*)d_in[11];
    const int*   mask    = (const int*)d_in[12];
    float* out = (float*)d_out;

    float* Qws = (float*)d_ws;             // B*D floats
    float* Uws = Qws + Bn * Dn;            // B*D floats

    k_q   <<<Bn,      128, 0, stream>>>(h_g, first, last, context, Wq, bq, Qws);
    k_attn<<<Bn * Hn, 256, 0, stream>>>(Qws, K, V, mask, Uws);
    k_ptr <<<Bn,      512, 0, stream>>>(Uws, Wo, bo, K_lg, mask, out);
}